// Round 4
// baseline (915.716 us; speedup 1.0000x reference)
//
#include <hip/hip_runtime.h>
#include <hip/hip_bf16.h>

// Fused masked attention fwd: out = softmax(mask(QK^T/8)) @ V, also emits attn.
// B=4 H=16 S=2048 D=64, fp32 in/out. Two-pass (denominator, then recompute+emit),
// no max-subtraction (scores ~N(0,1); exp stays in fp32 range).
//
// R4: phase 1 is BARRIER-FREE — K fragments loaded per-wave directly from
// global (L1/L2-shared across waves/blocks), half-tile (16-row) software
// pipeline, no LDS. Phase 2 keeps R3's dbuf + single raw-barrier structure.
// f32->bf16 now via __float2bfloat16 (compiler emits v_cvt_pk_bf16_f32).

typedef __attribute__((ext_vector_type(8))) short bf16x8;
typedef __attribute__((ext_vector_type(4))) float f32x4;
typedef __attribute__((ext_vector_type(4))) int i32x4;
typedef __attribute__((ext_vector_type(2))) unsigned int u32x2;

#define MFMA16(A, B, C) __builtin_amdgcn_mfma_f32_16x16x32_bf16((A), (B), (C), 0, 0, 0)

constexpr int Bsz = 4, Hsz = 16, Ssz = 2048, Dsz = 64;
constexpr int QBLK = 64;          // q-rows per workgroup
constexpr int KBLK = 64;          // k-cols per tile (phase 2)
constexpr int NTHR = 512;         // 8 waves: 4 q-blocks x 2 k-halves
constexpr int NT   = Ssz / KBLK;  // 32 tiles (phase 2)
constexpr int NH   = 64;          // phase-1 half-tiles per wave (16 k-rows each)
constexpr float SCALE = 0.125f;   // 1/sqrt(64)

static __device__ __forceinline__ short f2bf(float f) {
  // RNE via hardware cvt (compiler packs adjacent pairs into v_cvt_pk_bf16_f32)
  __hip_bfloat16 h = __float2bfloat16(f);
  return __builtin_bit_cast(short, h);
}

// Workgroup barrier WITHOUT the vmcnt(0) drain __syncthreads would emit.
static __device__ __forceinline__ void wg_barrier() {
  __builtin_amdgcn_sched_barrier(0);
  asm volatile("s_waitcnt lgkmcnt(0)" ::: "memory");
  __builtin_amdgcn_sched_barrier(0);
  __builtin_amdgcn_s_barrier();
  __builtin_amdgcn_sched_barrier(0);
}

__global__ __launch_bounds__(NTHR, 4)
void attn_fused(const float* __restrict__ Qg, const float* __restrict__ Kg,
                const float* __restrict__ Vg, const int* __restrict__ Mg,
                float* __restrict__ Og, float* __restrict__ Ag)
{
  // LDS (phase 2 only): sK[2][64][72] | sVt[2][64][72] | sP[64][72]
  __shared__ __align__(16) char smem[5 * 64 * 72 * 2];
  auto sK  = (short(*)[KBLK][72])(smem);              // [buf][k][d]
  auto sVt = (short(*)[Dsz][72])(smem + 2 * 9216);    // [buf][d][k]
  auto sP  = (short(*)[72])(smem + 4 * 9216);         // [q][k]
  auto sO  = (float(*)[68])(smem);                    // epilogue overlay [q][d]
  __shared__ float sL[2][QBLK];

  const int qt   = blockIdx.x;
  const int bh   = blockIdx.y;
  const int q0   = qt * QBLK;
  const int tid  = threadIdx.x;
  const int lane = tid & 63;
  const int wid  = tid >> 6;   // 0..7
  const int wq   = wid >> 1;   // 0..3: q-block of 16
  const int wk   = wid & 1;    // 0..1: k-half of 32 within KBLK
  const int lr   = lane & 15;  // q within 16-block (C col)
  const int lg   = lane >> 4;  // 0..3

  const size_t bhSD = (size_t)bh * (Ssz * Dsz);
  const float* Qb = Qg + bhSD;
  const float* Kb = Kg + bhSD;
  const float* Vb = Vg + bhSD;
  const int*   Mb = Mg + (size_t)(bh >> 4) * ((size_t)Ssz * Ssz);
  float*       Ob = Og + bhSD;
  float*       Ab = Ag + (size_t)bh * ((size_t)Ssz * Ssz);

  const int qrow = q0 + wq * 16 + lr;   // this lane's q-row (all its S/P work)
  const int* Mrow = Mb + (size_t)qrow * Ssz;
  float*     Arow = Ab + (size_t)qrow * Ssz;

  // ---- Q fragments (B-operand of swapped mfma), pre-scaled by 1/8 ----
  bf16x8 qf[2];
  {
    const float* qp = Qb + (size_t)qrow * Dsz + lg * 8;
#pragma unroll
    for (int h = 0; h < 2; ++h) {
      f32x4 a = *(const f32x4*)(qp + h * 32);
      f32x4 b = *(const f32x4*)(qp + h * 32 + 4);
      bf16x8 t;
#pragma unroll
      for (int j = 0; j < 4; ++j) { t[j] = f2bf(a[j] * SCALE); t[4 + j] = f2bf(b[j] * SCALE); }
      qf[h] = t;
    }
  }

  // ============ phase 1: softmax denominators (NO barriers, NO LDS) ============
  // Half-tile h covers k-rows [koff(h), koff(h)+16), koff = (h>>1)*64 + wk*32 + (h&1)*16.
  // Lane loads its A-fragment rows directly: K[koff+lr][d] for d in
  // {lg*8..+3, lg*8+4..+7, 32+lg*8..+3, 32+lg*8+4..+7}  (16 floats).
  float lacc = 0.f;
  {
    const float* Klane = Kb + (size_t)lr * Dsz + lg * 8;  // + koff*Dsz (+0/4/32/36)
    const int*   Mlane = Mrow + lg * 4;                   // + koff

    f32x4 L[4]; i32x4 mc;
    {  // prologue: half-tile 0
      const int koff = wk * 32;
      const float* kp = Klane + (size_t)koff * Dsz;
      L[0] = *(const f32x4*)(kp);
      L[1] = *(const f32x4*)(kp + 4);
      L[2] = *(const f32x4*)(kp + 32);
      L[3] = *(const f32x4*)(kp + 36);
      mc = *(const i32x4*)(Mlane + koff);
    }
    bf16x8 F0, F1;
#pragma unroll
    for (int j = 0; j < 4; ++j) {
      F0[j] = f2bf(L[0][j]); F0[4 + j] = f2bf(L[1][j]);
      F1[j] = f2bf(L[2][j]); F1[4 + j] = f2bf(L[3][j]);
    }

    for (int h = 0; h < NH; ++h) {
      f32x4 Ln[4]; i32x4 mn;
      if (h + 1 < NH) {  // issue next half-tile loads (consumed end of this iter)
        const int koff = ((h + 1) >> 1) * 64 + wk * 32 + ((h + 1) & 1) * 16;
        const float* kp = Klane + (size_t)koff * Dsz;
        Ln[0] = *(const f32x4*)(kp);
        Ln[1] = *(const f32x4*)(kp + 4);
        Ln[2] = *(const f32x4*)(kp + 32);
        Ln[3] = *(const f32x4*)(kp + 36);
        mn = *(const i32x4*)(Mlane + koff);
      }
      f32x4 c = {0.f, 0.f, 0.f, 0.f};
      c = MFMA16(F0, qf[0], c);   // C[k'][q]: col=lr=q, row=lg*4+r=k'
      c = MFMA16(F1, qf[1], c);
#pragma unroll
      for (int r = 0; r < 4; ++r) lacc += mc[r] ? __expf(c[r]) : 0.f;
      if (h + 1 < NH) {
#pragma unroll
        for (int j = 0; j < 4; ++j) {
          F0[j] = f2bf(Ln[0][j]); F0[4 + j] = f2bf(Ln[1][j]);
          F1[j] = f2bf(Ln[2][j]); F1[4 + j] = f2bf(Ln[3][j]);
        }
        mc = mn;
      }
    }
  }

  // lane's partial covers its (wk, lg) k-slots for q=qrow: reduce lg, then wk
  lacc += __shfl_xor(lacc, 16, 64);
  lacc += __shfl_xor(lacc, 32, 64);
  if (lane < 16) sL[wk][wq * 16 + lane] = lacc;
  wg_barrier();
  const float lsum = sL[0][wq * 16 + lr] + sL[1][wq * 16 + lr];
  const float invl = (lsum > 0.f) ? 1.f / lsum : 0.f;  // all-masked row -> 0

  // ================= phase 2: emit attn, accumulate O =================
  const int krow = tid >> 3;          // K staging: row
  const int kd0  = (tid & 7) * 8;     // K staging: d offset (8 contiguous)
  const int vkv  = tid & 63;          // V staging: k (one row per lane)
  const int vd0  = (tid >> 6) * 8;    // V staging: d offset (8 contiguous)
  const int kb0  = wk * 32 + lg * 4;  // lane's within-tile k base (cb=0)

  f32x4 oacc[4] = {{0,0,0,0},{0,0,0,0},{0,0,0,0},{0,0,0,0}};

  {  // stage K+V tile 0 into buf 0
    const float* kp = Kb + (size_t)krow * Dsz + kd0;
    f32x4 a = *(const f32x4*)kp;
    f32x4 b = *(const f32x4*)(kp + 4);
    bf16x8 t;
#pragma unroll
    for (int j = 0; j < 4; ++j) { t[j] = f2bf(a[j]); t[4 + j] = f2bf(b[j]); }
    *(bf16x8*)(&sK[0][krow][kd0]) = t;

    const float* vp = Vb + (size_t)vkv * Dsz + vd0;
    f32x4 va = *(const f32x4*)vp;
    f32x4 vb = *(const f32x4*)(vp + 4);
#pragma unroll
    for (int j = 0; j < 4; ++j) {
      sVt[0][vd0 + j][vkv]     = f2bf(va[j]);
      sVt[0][vd0 + 4 + j][vkv] = f2bf(vb[j]);
    }
  }
  i32x4 m0n = *(const i32x4*)(Mrow + kb0);
  i32x4 m1n = *(const i32x4*)(Mrow + kb0 + 16);
  wg_barrier();

  for (int t = 0; t < NT; ++t) {
    const int cur = t & 1;
    const i32x4 m0 = m0n, m1 = m1n;
    f32x4 ka = {0.f,0.f,0.f,0.f}, kb2 = {0.f,0.f,0.f,0.f};
    f32x4 va = {0.f,0.f,0.f,0.f}, vb2 = {0.f,0.f,0.f,0.f};
    if (t + 1 < NT) {  // issue next-tile loads early
      const float* kp = Kb + (size_t)((t + 1) * KBLK + krow) * Dsz + kd0;
      ka  = *(const f32x4*)kp;
      kb2 = *(const f32x4*)(kp + 4);
      const float* vp = Vb + (size_t)((t + 1) * KBLK + vkv) * Dsz + vd0;
      va  = *(const f32x4*)vp;
      vb2 = *(const f32x4*)(vp + 4);
      m0n = *(const i32x4*)(Mrow + (t + 1) * KBLK + kb0);
      m1n = *(const i32x4*)(Mrow + (t + 1) * KBLK + kb0 + 16);
    }
#pragma unroll
    for (int cb = 0; cb < 2; ++cb) {  // recompute S^T, emit attn, stage P
      const short* kr = &sK[cur][wk * 32 + cb * 16 + lr][0];
      bf16x8 a0 = *(const bf16x8*)(kr + lg * 8);
      bf16x8 a1 = *(const bf16x8*)(kr + 32 + lg * 8);
      f32x4 c = {0.f, 0.f, 0.f, 0.f};
      c = MFMA16(a0, qf[0], c);
      c = MFMA16(a1, qf[1], c);
      i32x4 mv = cb ? m1 : m0;
      f32x4 p;
#pragma unroll
      for (int r = 0; r < 4; ++r) p[r] = mv[r] ? __expf(c[r]) * invl : 0.f;
      // attn out: 4 consecutive k of one q-row -> dwordx4, nontemporal
      __builtin_nontemporal_store(p, (f32x4*)(Arow + t * KBLK + kb0 + cb * 16));
      // P tile bf16: b64 write into own-wave region (no barrier needed)
      unsigned plo = (unsigned short)f2bf(p[0]) | ((unsigned)(unsigned short)f2bf(p[1]) << 16);
      unsigned phi = (unsigned short)f2bf(p[2]) | ((unsigned)(unsigned short)f2bf(p[3]) << 16);
      u32x2 w = {plo, phi};
      *(u32x2*)(&sP[wq * 16 + lr][wk * 32 + cb * 16 + lg * 4]) = w;
    }
    // PV over OWN k-half only (own-wave sP region; LDS ops complete in order)
    bf16x8 pa = *(const bf16x8*)(&sP[wq * 16 + lr][wk * 32 + lg * 8]);
#pragma unroll
    for (int nb = 0; nb < 4; ++nb) {
      bf16x8 vb = *(const bf16x8*)(&sVt[cur][nb * 16 + lr][wk * 32 + lg * 8]);
      oacc[nb] = MFMA16(pa, vb, oacc[nb]);  // C[q'][d]: col=lr=d, row=lg*4+r=q'
    }
    if (t + 1 < NT) {  // write next K+V tiles into the other buffers (late write)
      bf16x8 tt;
#pragma unroll
      for (int j = 0; j < 4; ++j) { tt[j] = f2bf(ka[j]); tt[4 + j] = f2bf(kb2[j]); }
      *(bf16x8*)(&sK[cur ^ 1][krow][kd0]) = tt;
#pragma unroll
      for (int j = 0; j < 4; ++j) {
        sVt[cur ^ 1][vd0 + j][vkv]     = f2bf(va[j]);   // 2-way same-word b16: free
        sVt[cur ^ 1][vd0 + 4 + j][vkv] = f2bf(vb2[j]);
      }
    }
    wg_barrier();
  }

  // ---- epilogue: sum the two wk-halves of O via LDS overlay, write out ----
  if (wk == 0) {
#pragma unroll
    for (int nb = 0; nb < 4; ++nb)
#pragma unroll
      for (int r = 0; r < 4; ++r)
        sO[wq * 16 + lg * 4 + r][nb * 16 + lr] = oacc[nb][r];
  }
  wg_barrier();
  if (wk == 1) {
#pragma unroll
    for (int nb = 0; nb < 4; ++nb)
#pragma unroll
      for (int r = 0; r < 4; ++r) {
        float v = sO[wq * 16 + lg * 4 + r][nb * 16 + lr] + oacc[nb][r];
        __builtin_nontemporal_store(v, Ob + (size_t)(q0 + wq * 16 + lg * 4 + r) * Dsz + nb * 16 + lr);
      }
  }
}

extern "C" void kernel_launch(void* const* d_in, const int* in_sizes, int n_in,
                              void* d_out, int out_size, void* d_ws, size_t ws_size,
                              hipStream_t stream) {
  const float* Q = (const float*)d_in[0];
  const float* K = (const float*)d_in[1];
  const float* V = (const float*)d_in[2];
  const int*   M = (const int*)d_in[3];
  float* Out  = (float*)d_out;
  float* Attn = Out + (size_t)Bsz * Hsz * Ssz * Dsz;  // outputs concatenated: (out, attn)
  dim3 grid(Ssz / QBLK, Bsz * Hsz);
  attn_fused<<<grid, NTHR, 0, stream>>>(Q, K, V, M, Out, Attn);
}

// Round 5
// 504.831 us; speedup vs baseline: 1.8139x; 1.8139x over previous
//
#include <hip/hip_runtime.h>
#include <hip/hip_bf16.h>

// Fused masked attention fwd: out = softmax(mask(QK^T/8)) @ V, also emits attn.
// B=4 H=16 S=2048 D=64, fp32 in/out. Two KERNELS:
//   1) attn_denom: softmax denominators -> invl in ws; mask bit-packed to ws.
//      128 q-rows/block, 18KB LDS, 100% occupancy, barrier only for K staging.
//   2) attn_emit: recompute S, write attn (NT dwordx4), accumulate O=PV.
//      R3 structure (dbuf LDS, raw-barrier, no vmcnt drain) + ushort mask bits
//      + invl from ws + s_setprio around MFMA/exp cluster.
// No max-subtraction (scores ~N(0,1); exp stays in fp32 range).

typedef __attribute__((ext_vector_type(8))) short bf16x8;
typedef __attribute__((ext_vector_type(4))) float f32x4;
typedef __attribute__((ext_vector_type(4))) int i32x4;
typedef __attribute__((ext_vector_type(2))) unsigned int u32x2;

#define MFMA16(A, B, C) __builtin_amdgcn_mfma_f32_16x16x32_bf16((A), (B), (C), 0, 0, 0)

constexpr int Bsz = 4, Hsz = 16, Ssz = 2048, Dsz = 64;
constexpr int KBLK = 64;          // k-cols per tile
constexpr int NT   = Ssz / KBLK;  // 32 tiles
constexpr float SCALE = 0.125f;   // 1/sqrt(64)

static __device__ __forceinline__ short f2bf(float f) {
  __hip_bfloat16 h = __float2bfloat16(f);   // hw cvt; pairs fuse to v_cvt_pk_bf16_f32
  return __builtin_bit_cast(short, h);
}

// Workgroup barrier WITHOUT the vmcnt(0) drain __syncthreads would emit:
// LDS writes visible (lgkmcnt 0), global loads/stores stay in flight.
static __device__ __forceinline__ void wg_barrier() {
  __builtin_amdgcn_sched_barrier(0);
  asm volatile("s_waitcnt lgkmcnt(0)" ::: "memory");
  __builtin_amdgcn_sched_barrier(0);
  __builtin_amdgcn_s_barrier();
  __builtin_amdgcn_sched_barrier(0);
}

// ---------------- kernel 1: denominators + mask bit-pack ----------------
// grid (Ssz/128, B*H), 512 thr. Wave w owns q-rows [q0+w*16, +16), full k.
__global__ __launch_bounds__(512, 8)
void attn_denom(const float* __restrict__ Qg, const float* __restrict__ Kg,
                const int* __restrict__ Mg, float* __restrict__ wsL,
                unsigned short* __restrict__ wsM)
{
  __shared__ short sK[2][KBLK][72];   // 18432 B -> 4 blocks/CU (wave-capped)

  const int qt = blockIdx.x, bh = blockIdx.y;
  const int q0 = qt * 128;
  const int tid = threadIdx.x, lane = tid & 63, w = tid >> 6;
  const int lr = lane & 15, lg = lane >> 4;

  const size_t bhSD = (size_t)bh * (Ssz * Dsz);
  const float* Qb = Qg + bhSD;
  const float* Kb = Kg + bhSD;
  const int b = bh >> 4;
  const int qrow = q0 + w * 16 + lr;
  const int* Mrow = Mg + ((size_t)b * Ssz + qrow) * Ssz;
  // bits for (b,qrow): 32 tiles x 4 lg ushorts = 128 ushorts (256 B) per row.
  unsigned short* wsMq = wsM + (size_t)(b * Ssz + qrow) * (NT * 4) + lg;

  // Q fragments (B-operand of swapped mfma), pre-scaled by 1/8
  bf16x8 qf[2];
  {
    const float* qp = Qb + (size_t)qrow * Dsz + lg * 8;
#pragma unroll
    for (int h = 0; h < 2; ++h) {
      f32x4 a = *(const f32x4*)(qp + h * 32);
      f32x4 c2 = *(const f32x4*)(qp + h * 32 + 4);
      bf16x8 t;
#pragma unroll
      for (int j = 0; j < 4; ++j) { t[j] = f2bf(a[j] * SCALE); t[4 + j] = f2bf(c2[j] * SCALE); }
      qf[h] = t;
    }
  }

  const int krow = tid >> 3, kd0 = (tid & 7) * 8;
  {  // prologue: stage K tile 0
    const float* kp = Kb + (size_t)krow * Dsz + kd0;
    f32x4 a = *(const f32x4*)kp, c2 = *(const f32x4*)(kp + 4);
    bf16x8 t;
#pragma unroll
    for (int j = 0; j < 4; ++j) { t[j] = f2bf(a[j]); t[4 + j] = f2bf(c2[j]); }
    *(bf16x8*)(&sK[0][krow][kd0]) = t;
  }
  wg_barrier();

  float lacc = 0.f;
  for (int t = 0; t < NT; ++t) {
    const int cur = t & 1;
    f32x4 ka = {0.f,0.f,0.f,0.f}, kb2 = {0.f,0.f,0.f,0.f};
    if (t + 1 < NT) {  // next K tile -> regs (latency hides under compute)
      const float* kp = Kb + (size_t)((t + 1) * KBLK + krow) * Dsz + kd0;
      ka  = *(const f32x4*)kp;
      kb2 = *(const f32x4*)(kp + 4);
    }
    unsigned bits = 0;
#pragma unroll
    for (int cb = 0; cb < 4; ++cb) {
      const short* kr = &sK[cur][cb * 16 + lr][0];
      bf16x8 a0 = *(const bf16x8*)(kr + lg * 8);
      bf16x8 a1 = *(const bf16x8*)(kr + 32 + lg * 8);
      f32x4 c = {0.f, 0.f, 0.f, 0.f};
      c = MFMA16(a0, qf[0], c);   // C[k'][q]: col=lr=q, row=lg*4+r=k'
      c = MFMA16(a1, qf[1], c);
      i32x4 mv = *(const i32x4*)(Mrow + t * KBLK + cb * 16 + lg * 4);
#pragma unroll
      for (int r = 0; r < 4; ++r) {
        lacc += mv[r] ? __expf(c[r]) : 0.f;
        bits |= (mv[r] ? 1u : 0u) << (cb * 4 + r);
      }
    }
    wsMq[t * 4] = (unsigned short)bits;  // heads sharing b write identical values
    if (t + 1 < NT) {  // write staged tile into other buffer
      bf16x8 t2;
#pragma unroll
      for (int j = 0; j < 4; ++j) { t2[j] = f2bf(ka[j]); t2[4 + j] = f2bf(kb2[j]); }
      *(bf16x8*)(&sK[cur ^ 1][krow][kd0]) = t2;
    }
    wg_barrier();
  }

  // reduce over lg (lanes lr, lr+16, lr+32, lr+48 share qrow): full row sum
  lacc += __shfl_xor(lacc, 16, 64);
  lacc += __shfl_xor(lacc, 32, 64);
  if (lane < 16)
    wsL[(size_t)bh * Ssz + qrow] = (lacc > 0.f) ? 1.f / lacc : 0.f;
}

// ---------------- kernel 2: emit attn + O = PV ----------------
// grid (Ssz/64, B*H), 512 thr: 4 q-blocks x 2 k-halves.
__global__ __launch_bounds__(512, 6)
void attn_emit(const float* __restrict__ Qg, const float* __restrict__ Kg,
               const float* __restrict__ Vg, const float* __restrict__ wsL,
               const unsigned short* __restrict__ wsM,
               float* __restrict__ Og, float* __restrict__ Ag)
{
  // sK[2][64][72] | sVt[2][64][72] | sP[64][72]  (46080 B -> 3 blocks/CU)
  __shared__ __align__(16) char smem[5 * 64 * 72 * 2];
  auto sK  = (short(*)[KBLK][72])(smem);
  auto sVt = (short(*)[Dsz][72])(smem + 2 * 9216);
  auto sP  = (short(*)[72])(smem + 4 * 9216);
  auto sO  = (float(*)[68])(smem);   // epilogue overlay

  const int qt = blockIdx.x, bh = blockIdx.y;
  const int q0 = qt * 64;
  const int tid = threadIdx.x, lane = tid & 63, wid = tid >> 6;
  const int wq = wid >> 1, wk = wid & 1;
  const int lr = lane & 15, lg = lane >> 4;

  const size_t bhSD = (size_t)bh * (Ssz * Dsz);
  const float* Qb = Qg + bhSD;
  const float* Kb = Kg + bhSD;
  const float* Vb = Vg + bhSD;
  const int b = bh >> 4;
  float* Ob = Og + bhSD;
  float* Ab = Ag + (size_t)bh * ((size_t)Ssz * Ssz);

  const int qrow = q0 + wq * 16 + lr;
  float* Arow = Ab + (size_t)qrow * Ssz;
  const float invl = wsL[(size_t)bh * Ssz + qrow];
  const unsigned short* wsMq = wsM + (size_t)(b * Ssz + qrow) * (NT * 4) + lg;
  const int mshift = wk * 8;

  bf16x8 qf[2];
  {
    const float* qp = Qb + (size_t)qrow * Dsz + lg * 8;
#pragma unroll
    for (int h = 0; h < 2; ++h) {
      f32x4 a = *(const f32x4*)(qp + h * 32);
      f32x4 c2 = *(const f32x4*)(qp + h * 32 + 4);
      bf16x8 t;
#pragma unroll
      for (int j = 0; j < 4; ++j) { t[j] = f2bf(a[j] * SCALE); t[4 + j] = f2bf(c2[j] * SCALE); }
      qf[h] = t;
    }
  }

  const int krow = tid >> 3;          // K staging: row
  const int kd0  = (tid & 7) * 8;     // K staging: d offset
  const int vkv  = tid & 63;          // V staging: k
  const int vd0  = (tid >> 6) * 8;    // V staging: d offset
  const int kb0  = wk * 32 + lg * 4;  // lane's within-tile k base (cb=0)

  f32x4 oacc[4] = {{0,0,0,0},{0,0,0,0},{0,0,0,0},{0,0,0,0}};

  {  // prologue: stage K+V tile 0
    const float* kp = Kb + (size_t)krow * Dsz + kd0;
    f32x4 a = *(const f32x4*)kp, c2 = *(const f32x4*)(kp + 4);
    bf16x8 t;
#pragma unroll
    for (int j = 0; j < 4; ++j) { t[j] = f2bf(a[j]); t[4 + j] = f2bf(c2[j]); }
    *(bf16x8*)(&sK[0][krow][kd0]) = t;

    const float* vp = Vb + (size_t)vkv * Dsz + vd0;
    f32x4 va = *(const f32x4*)vp, vb = *(const f32x4*)(vp + 4);
#pragma unroll
    for (int j = 0; j < 4; ++j) {
      sVt[0][vd0 + j][vkv]     = f2bf(va[j]);
      sVt[0][vd0 + 4 + j][vkv] = f2bf(vb[j]);
    }
  }
  unsigned mbn = wsMq[0];
  wg_barrier();

  for (int t = 0; t < NT; ++t) {
    const int cur = t & 1;
    const unsigned mb = mbn;
    f32x4 ka = {0.f,0.f,0.f,0.f}, kb2 = {0.f,0.f,0.f,0.f};
    f32x4 va = {0.f,0.f,0.f,0.f}, vb2 = {0.f,0.f,0.f,0.f};
    if (t + 1 < NT) {  // next-tile loads issued early
      const float* kp = Kb + (size_t)((t + 1) * KBLK + krow) * Dsz + kd0;
      ka  = *(const f32x4*)kp;
      kb2 = *(const f32x4*)(kp + 4);
      const float* vp = Vb + (size_t)((t + 1) * KBLK + vkv) * Dsz + vd0;
      va  = *(const f32x4*)vp;
      vb2 = *(const f32x4*)(vp + 4);
      mbn = wsMq[(t + 1) * 4];
    }
    __builtin_amdgcn_s_setprio(1);    // favor this wave through MFMA/exp cluster
#pragma unroll
    for (int cb = 0; cb < 2; ++cb) {  // recompute S^T, emit attn, stage P
      const short* kr = &sK[cur][wk * 32 + cb * 16 + lr][0];
      bf16x8 a0 = *(const bf16x8*)(kr + lg * 8);
      bf16x8 a1 = *(const bf16x8*)(kr + 32 + lg * 8);
      f32x4 c = {0.f, 0.f, 0.f, 0.f};
      c = MFMA16(a0, qf[0], c);
      c = MFMA16(a1, qf[1], c);
      f32x4 p;
#pragma unroll
      for (int r = 0; r < 4; ++r)
        p[r] = ((mb >> (mshift + cb * 4 + r)) & 1u) ? __expf(c[r]) * invl : 0.f;
      __builtin_nontemporal_store(p, (f32x4*)(Arow + t * KBLK + kb0 + cb * 16));
      unsigned plo = (unsigned short)f2bf(p[0]) | ((unsigned)(unsigned short)f2bf(p[1]) << 16);
      unsigned phi = (unsigned short)f2bf(p[2]) | ((unsigned)(unsigned short)f2bf(p[3]) << 16);
      u32x2 wv = {plo, phi};
      *(u32x2*)(&sP[wq * 16 + lr][wk * 32 + cb * 16 + lg * 4]) = wv;
    }
    // PV over OWN k-half (own-wave sP region; LDS ops complete in order)
    bf16x8 pa = *(const bf16x8*)(&sP[wq * 16 + lr][wk * 32 + lg * 8]);
#pragma unroll
    for (int nb = 0; nb < 4; ++nb) {
      bf16x8 vb = *(const bf16x8*)(&sVt[cur][nb * 16 + lr][wk * 32 + lg * 8]);
      oacc[nb] = MFMA16(pa, vb, oacc[nb]);  // C[q'][d]: col=lr=d, row=lg*4+r=q'
    }
    __builtin_amdgcn_s_setprio(0);
    if (t + 1 < NT) {  // late staging writes into other buffers
      bf16x8 t2;
#pragma unroll
      for (int j = 0; j < 4; ++j) { t2[j] = f2bf(ka[j]); t2[4 + j] = f2bf(kb2[j]); }
      *(bf16x8*)(&sK[cur ^ 1][krow][kd0]) = t2;
#pragma unroll
      for (int j = 0; j < 4; ++j) {
        sVt[cur ^ 1][vd0 + j][vkv]     = f2bf(va[j]);
        sVt[cur ^ 1][vd0 + 4 + j][vkv] = f2bf(vb2[j]);
      }
    }
    wg_barrier();
  }

  // epilogue: sum the two wk-halves of O via LDS overlay, write out
  if (wk == 0) {
#pragma unroll
    for (int nb = 0; nb < 4; ++nb)
#pragma unroll
      for (int r = 0; r < 4; ++r)
        sO[wq * 16 + lg * 4 + r][nb * 16 + lr] = oacc[nb][r];
  }
  wg_barrier();
  if (wk == 1) {
#pragma unroll
    for (int nb = 0; nb < 4; ++nb)
#pragma unroll
      for (int r = 0; r < 4; ++r) {
        float v = sO[wq * 16 + lg * 4 + r][nb * 16 + lr] + oacc[nb][r];
        __builtin_nontemporal_store(v, Ob + (size_t)(q0 + wq * 16 + lg * 4 + r) * Dsz + nb * 16 + lr);
      }
  }
}

extern "C" void kernel_launch(void* const* d_in, const int* in_sizes, int n_in,
                              void* d_out, int out_size, void* d_ws, size_t ws_size,
                              hipStream_t stream) {
  const float* Q = (const float*)d_in[0];
  const float* K = (const float*)d_in[1];
  const float* V = (const float*)d_in[2];
  const int*   M = (const int*)d_in[3];
  float* Out  = (float*)d_out;
  float* Attn = Out + (size_t)Bsz * Hsz * Ssz * Dsz;  // outputs concatenated
  // ws layout: [invl: B*H*S fp32 = 512KB][maskbits: B*S*128 ushort = 2MB]
  float* wsL = (float*)d_ws;
  unsigned short* wsM = (unsigned short*)((char*)d_ws + (size_t)Bsz * Hsz * Ssz * sizeof(float));
  attn_denom<<<dim3(Ssz / 128, Bsz * Hsz), 512, 0, stream>>>(Q, K, M, wsL, wsM);
  attn_emit <<<dim3(Ssz / 64,  Bsz * Hsz), 512, 0, stream>>>(Q, K, V, wsL, wsM, Out, Attn);
}